// Round 15
// baseline (139.890 us; speedup 1.0000x reference)
//
#include <hip/hip_runtime.h>
#include <cstdint>

#define HEADS 8
#define HD 64
#define NQ 4096
#define NKV 1024

typedef unsigned short u16;
typedef __attribute__((ext_vector_type(8))) short short8;
typedef __attribute__((ext_vector_type(4))) float f32x4;
typedef __attribute__((ext_vector_type(16))) float f32x16;

__device__ __forceinline__ u16 f2bf(float f){
  union { float f; unsigned u; } c; c.f = f;
  unsigned r = c.u + 0x7fffu + ((c.u >> 16) & 1u);
  return (u16)(r >> 16);
}
__device__ __forceinline__ unsigned pack2(float a, float b){
  return (unsigned)f2bf(a) | ((unsigned)f2bf(b) << 16);
}
__device__ __forceinline__ float fexp2(float x){
  float r;
  asm("v_exp_f32 %0, %1" : "=v"(r) : "v"(x));
  return r;
}
__device__ __forceinline__ unsigned cvtpk(float a, float b){
  unsigned r;
  asm("v_cvt_pk_bf16_f32 %0, %1, %2" : "=v"(r) : "v"(a), "v"(b));
  return r;
}
__device__ __forceinline__ void gll16(const void* g, void* l){
  __builtin_amdgcn_global_load_lds((const __attribute__((address_space(1))) unsigned*)g,
                                   (__attribute__((address_space(3))) unsigned*)l, 16, 0, 0);
}
#define SB0() __builtin_amdgcn_sched_barrier(0)
#define MFMA16(a, b, c) __builtin_amdgcn_mfma_f32_16x16x32_bf16(a, b, c, 0, 0, 0)
#define MFMA32(a, b, c) __builtin_amdgcn_mfma_f32_32x32x16_bf16(a, b, c, 0, 0, 0)
#define Z16 {0.f,0.f,0.f,0.f,0.f,0.f,0.f,0.f,0.f,0.f,0.f,0.f,0.f,0.f,0.f,0.f}

// ---- merged prep: x -> bf16 token layout; weights -> bf16 [N][K] ----
__global__ __launch_bounds__(256) void prep_all(const float* __restrict__ x,
                                                const float* __restrict__ q_w,
                                                const float* __restrict__ kv_w,
                                                const float* __restrict__ proj_w,
                                                const float* __restrict__ sr_w,
                                                u16* __restrict__ x_bf,
                                                u16* __restrict__ q_wT, u16* __restrict__ kv_wT,
                                                u16* __restrict__ proj_wT, u16* __restrict__ conv_BT){
  int bid = blockIdx.x;
  if (bid < 4096){
    int tid = bid * 256 + threadIdx.x;
    size_t src = (size_t)tid * 8;
    const float4* s4 = (const float4*)(x + src);
    float4 v0 = s4[0], v1 = s4[1];
    uint4 p;
    p.x = pack2(v0.x, v0.y); p.y = pack2(v0.z, v0.w);
    p.z = pack2(v1.x, v1.y); p.w = pack2(v1.z, v1.w);
    *(uint4*)(x_bf + src) = p;
    return;
  }
  int e = (bid - 4096) * 256 + threadIdx.x;
  if (e < 262144){ int n = e >> 9, k = e & 511; q_wT[e] = f2bf(q_w[k * 512 + n]); return; }
  e -= 262144;
  if (e < 524288){ int n = e >> 9, k = e & 511; kv_wT[e] = f2bf(kv_w[k * 1024 + n]); return; }
  e -= 524288;
  if (e < 262144){ int n = e >> 9, k = e & 511; proj_wT[e] = f2bf(proj_w[k * 512 + n]); return; }
  e -= 262144;
  { int co = e >> 11, r = e & 2047, t = r >> 9, ci = r & 511;
    conv_BT[e] = f2bf(sr_w[co * 2048 + ci * 4 + t]); }
}

// ---- fused conv-GEMM + q-GEMM, UNIFORM 8-iter blocks. grid (4, 256):
// y<128 -> conv split-K4 (kz=y>>5, one conv tap per kz); y>=128 -> q.
// A read from x_bf (conv via patch remap). 128x128 tile, BK=64.
__global__ __launch_bounds__(256) void gemm_qconv(const u16* __restrict__ x_bf, const u16* __restrict__ q_wT,
                                                  const u16* __restrict__ conv_BT,
                                                  u16* __restrict__ q_sb, float* __restrict__ parts,
                                                  const float* __restrict__ sr_b){
  __shared__ __align__(16) u16 As[128 * 64];
  __shared__ __align__(16) u16 Bs[128 * 64];
  const int tid = threadIdx.x, lane = tid & 63, wave = tid >> 6;
  const int l15 = lane & 15, g = lane >> 4, r7 = l15 & 7;
  const int wr = wave >> 1, wc = wave & 1;
  int y = blockIdx.y;
  const bool isQ = (y >= 128);
  int kz = 0, m0, KB;
  const u16* BT;
  unsigned aTap = 0, bTap = 0;
  if (isQ){ m0 = (y - 128) * 128; KB = 512;  BT = q_wT; }
  else { kz = y >> 5; m0 = (y & 31) * 128; KB = 2048; BT = conv_BT;
         aTap = (unsigned)(((kz >> 1) * 64 + (kz & 1)) * 512);
         bTap = (unsigned)(kz << 9); }
  const int n0 = blockIdx.x * 128;

  unsigned aBase[4], bBase[4];
  #pragma unroll
  for (int ii = 0; ii < 4; ++ii){
    int c = ii * 256 + tid;
    int row = c >> 3, sc = (c & 7) ^ (row & 7);
    if (isQ) aBase[ii] = (unsigned)(m0 + row) * 512 + sc * 8;
    else { int grow = m0 + row, b = grow >> 10, pr = grow & 1023;
           aBase[ii] = ((unsigned)(b * 4096) + (pr >> 5) * 128 + (pr & 31) * 2) * 512 + sc * 8; }
    bBase[ii] = (unsigned)(n0 + row) * KB + sc * 8;
  }

  f32x4 acc[4][4] = {};
  for (int i = 0; i < 8; ++i){
    unsigned aOff = aTap + i * 64, bOff = bTap + i * 64;
    #pragma unroll
    for (int ii = 0; ii < 4; ++ii){
      gll16(x_bf + aBase[ii] + aOff, As + (size_t)(ii * 256 + wave * 64) * 8);
      gll16(BT + bBase[ii] + bOff,   Bs + (size_t)(ii * 256 + wave * 64) * 8);
    }
    __syncthreads();
    #pragma unroll
    for (int kk = 0; kk < 2; ++kk){
      short8 af[4];
      #pragma unroll
      for (int mi = 0; mi < 4; ++mi)
        af[mi] = *(const short8*)(As + (wr * 64 + mi * 16 + l15) * 64 + (((kk * 4 + g) ^ r7) << 3));
      #pragma unroll
      for (int ni = 0; ni < 4; ++ni){
        short8 bf = *(const short8*)(Bs + (wc * 64 + ni * 16 + l15) * 64 + (((kk * 4 + g) ^ r7) << 3));
        #pragma unroll
        for (int mi = 0; mi < 4; ++mi)
          acc[mi][ni] = MFMA16(af[mi], bf, acc[mi][ni]);
      }
    }
    __syncthreads();
  }
  #pragma unroll
  for (int mi = 0; mi < 4; ++mi){
    int row = m0 + wr * 64 + mi * 16 + (lane >> 4) * 4;
    #pragma unroll
    for (int ni = 0; ni < 4; ++ni){
      int col = n0 + wc * 64 + ni * 16 + l15;
      f32x4 v = acc[mi][ni];
      if (isQ){
        int h = col >> 6, d = col & 63;
        #pragma unroll
        for (int j = 0; j < 4; ++j){
          int r = row + j, b = r >> 12, nq = r & 4095;
          q_sb[(((size_t)(b * HEADS + h)) * NQ + nq) * HD + d] = f2bf(v[j] * 0.18033688f);
        }
      } else {
        float* Co = parts + (size_t)kz * 4096 * 512;
        float bb = (kz == 0) ? sr_b[col] : 0.f;
        #pragma unroll
        for (int j = 0; j < 4; ++j) Co[(size_t)(row + j) * 512 + col] = v[j] + bb;
      }
    }
  }
}

// ---- kv-GEMM: 64x128 tile, BK=64, 4 waves (2x2), grid (8,64) = 2/CU ----
__global__ __launch_bounds__(256) void gemm_kv(const u16* __restrict__ A, const u16* __restrict__ BT,
                                               u16* __restrict__ Cb0, u16* __restrict__ Cb1){
  __shared__ __align__(16) u16 As[64 * 64];
  __shared__ __align__(16) u16 Bs[128 * 64];
  const int tid = threadIdx.x, lane = tid & 63, wave = tid >> 6;
  const int l15 = lane & 15, g = lane >> 4, r7 = l15 & 7;
  const int m0 = blockIdx.y * 64, n0 = blockIdx.x * 128;
  const int wr = wave >> 1, wc = wave & 1;
  f32x4 acc[2][4] = {};
  for (int kt = 0; kt < 512; kt += 64){
    #pragma unroll
    for (int i = 0; i < 2; ++i){
      int c = i * 256 + tid;
      int row = c >> 3, sc = (c & 7) ^ (row & 7);
      gll16(A + (size_t)(m0 + row) * 512 + kt + sc * 8, As + (size_t)(i * 256 + wave * 64) * 8);
    }
    #pragma unroll
    for (int i = 0; i < 4; ++i){
      int c = i * 256 + tid;
      int row = c >> 3, sc = (c & 7) ^ (row & 7);
      gll16(BT + (size_t)(n0 + row) * 512 + kt + sc * 8, Bs + (size_t)(i * 256 + wave * 64) * 8);
    }
    __syncthreads();
    #pragma unroll
    for (int kk = 0; kk < 2; ++kk){
      short8 af[2];
      #pragma unroll
      for (int mi = 0; mi < 2; ++mi)
        af[mi] = *(const short8*)(As + (wr * 32 + mi * 16 + l15) * 64 + (((kk * 4 + g) ^ r7) << 3));
      #pragma unroll
      for (int ni = 0; ni < 4; ++ni){
        short8 bf = *(const short8*)(Bs + (wc * 64 + ni * 16 + l15) * 64 + (((kk * 4 + g) ^ r7) << 3));
        #pragma unroll
        for (int mi = 0; mi < 2; ++mi)
          acc[mi][ni] = MFMA16(af[mi], bf, acc[mi][ni]);
      }
    }
    __syncthreads();
  }
  #pragma unroll
  for (int mi = 0; mi < 2; ++mi){
    int row = m0 + wr * 32 + mi * 16 + (lane >> 4) * 4;
    #pragma unroll
    for (int ni = 0; ni < 4; ++ni){
      int col = n0 + wc * 64 + ni * 16 + l15;
      f32x4 v = acc[mi][ni];
      int s = col >> 9, h = (col >> 6) & 7, d = col & 63;
      if (s == 0){
        #pragma unroll
        for (int j = 0; j < 4; ++j){
          int r = row + j, b = r >> 10, p = r & 1023;
          Cb0[(((size_t)(b * HEADS + h)) * NKV + p) * HD + d] = f2bf(v[j]);
        }
      } else {                  // V^T: [bh][d][pi(p)], pi = swap quads 1<->2 per 16-block
        int b = row >> 10, p0 = row & 1023;
        int pp = (p0 & ~12) | (((p0 >> 2) & 1) << 3) | (((p0 >> 3) & 1) << 2);
        ushort4 pk;
        pk.x = f2bf(v[0]); pk.y = f2bf(v[1]); pk.z = f2bf(v[2]); pk.w = f2bf(v[3]);
        *(ushort4*)(Cb1 + (((size_t)(b * HEADS + h)) * HD + d) * NKV + pp) = pk;
      }
    }
  }
}

// ---- proj GEMM: C[M,N] = A[M,K] @ BT[N,K]^T, 128x128, BK=64, fp32 out (+bias) ----
__global__ __launch_bounds__(256) void gemm_proj(const u16* __restrict__ A, const u16* __restrict__ BT,
                                                 float* __restrict__ Cf, const float* __restrict__ bias,
                                                 int M, int N, int K){
  __shared__ __align__(16) u16 As[128 * 64];
  __shared__ __align__(16) u16 Bs[128 * 64];
  const int tid = threadIdx.x, lane = tid & 63, wave = tid >> 6;
  const int l15 = lane & 15, g = lane >> 4, r7 = l15 & 7;
  const int m0 = blockIdx.y * 128, n0 = blockIdx.x * 128;
  const int wr = wave >> 1, wc = wave & 1;
  f32x4 acc[4][4] = {};
  for (int kt = 0; kt < K; kt += 64){
    #pragma unroll
    for (int i = 0; i < 4; ++i){
      int c = i * 256 + tid;
      int row = c >> 3, sc = (c & 7) ^ (row & 7);
      gll16(A  + (size_t)(m0 + row) * K + kt + sc * 8, As + (size_t)(i * 256 + wave * 64) * 8);
      gll16(BT + (size_t)(n0 + row) * K + kt + sc * 8, Bs + (size_t)(i * 256 + wave * 64) * 8);
    }
    __syncthreads();
    #pragma unroll
    for (int kk = 0; kk < 2; ++kk){
      short8 af[4];
      #pragma unroll
      for (int mi = 0; mi < 4; ++mi)
        af[mi] = *(const short8*)(As + (wr * 64 + mi * 16 + l15) * 64 + (((kk * 4 + g) ^ r7) << 3));
      #pragma unroll
      for (int ni = 0; ni < 4; ++ni){
        short8 bf = *(const short8*)(Bs + (wc * 64 + ni * 16 + l15) * 64 + (((kk * 4 + g) ^ r7) << 3));
        #pragma unroll
        for (int mi = 0; mi < 4; ++mi)
          acc[mi][ni] = MFMA16(af[mi], bf, acc[mi][ni]);
      }
    }
    __syncthreads();
  }
  #pragma unroll
  for (int mi = 0; mi < 4; ++mi){
    int row = m0 + wr * 64 + mi * 16 + (lane >> 4) * 4;
    #pragma unroll
    for (int ni = 0; ni < 4; ++ni){
      int col = n0 + wc * 64 + ni * 16 + l15;
      f32x4 v = acc[mi][ni];
      float bb = bias[col];
      #pragma unroll
      for (int j = 0; j < 4; ++j) Cf[(size_t)(row + j) * N + col] = v[j] + bb;
    }
  }
}

// ---- LayerNorm over 512 cols; sums FOUR split-K partials; fp32 in, bf16 out ----
__global__ __launch_bounds__(256) void ln_k(const float* __restrict__ parts,
                                            const float* __restrict__ w,
                                            const float* __restrict__ bias, u16* __restrict__ xr){
  int row = blockIdx.x * 4 + (threadIdx.x >> 6);
  int lane = threadIdx.x & 63;
  const float* s1 = parts + (size_t)row * 512;
  const float* s2 = s1 + (size_t)4096 * 512;
  const float* s3 = s2 + (size_t)4096 * 512;
  const float* s4 = s3 + (size_t)4096 * 512;
  float vals[8]; float s = 0.f, ss = 0.f;
  #pragma unroll
  for (int j = 0; j < 8; ++j){
    int c = lane + j * 64;
    float v = (s1[c] + s2[c]) + (s3[c] + s4[c]);
    vals[j] = v; s += v; ss += v * v;
  }
  #pragma unroll
  for (int off = 32; off >= 1; off >>= 1){ s += __shfl_xor(s, off); ss += __shfl_xor(ss, off); }
  float mean = s * (1.f / 512.f);
  float var  = ss * (1.f / 512.f) - mean * mean;
  float rs = rsqrtf(var + 1e-5f);
  u16* dst = xr + (size_t)row * 512;
  #pragma unroll
  for (int j = 0; j < 8; ++j){
    int c = lane + j * 64;
    dst[c] = f2bf((vals[j] - mean) * rs * w[c] + bias[c]);
  }
}

// ---- flash attention v13: LOOPED tile body, 2 waves x 64 q-rows ----
// q pre-scaled by (1/8)*log2(e) so p = 2^s; no-max softmax; zero-shuffle PV (pi-V).
__global__ __launch_bounds__(128) void attn_k(const u16* __restrict__ q_s, const u16* __restrict__ k_s,
                                              const u16* __restrict__ vt_s, u16* __restrict__ net){
  __shared__ __align__(16) u16 Ks[2][64 * 64];
  __shared__ __align__(16) u16 Vt[2][64 * 64];
  const int tid = threadIdx.x, lane = tid & 63, wave = tid >> 6;
  const int l31 = lane & 31, hi = lane >> 5, x7 = lane & 7;
  const int id = blockIdx.x;
  const int xcd = id & 7, slot = id >> 3;
  const int bh = 4 * xcd + (slot >> 5);
  const int qblk = slot & 31;
  const u16* kb  = k_s  + (size_t)bh * NKV * HD;
  const u16* vtb = vt_s + (size_t)bh * HD * NKV;
  const int q0 = qblk * 128 + wave * 64;
  const u16* qbase = q_s + ((size_t)bh * NQ + q0 + l31) * HD + hi * 8;
  short8 qfA[4], qfB[4];
  #pragma unroll
  for (int ks = 0; ks < 4; ++ks){
    qfA[ks] = *(const short8*)(qbase + ks * 16);
    qfB[ks] = *(const short8*)(qbase + 32 * HD + ks * 16);
  }

  // per-lane pre-swizzled global staging addresses (chunk ^= row&7; LDS stays linear)
  const int swz8 = (((tid & 7) ^ ((tid >> 3) & 7)) << 3);
  const u16* ak0 = kb  + (size_t)(tid >> 3) * 64   + swz8;
  const u16* av0 = vtb + (size_t)(tid >> 3) * 1024 + swz8;

  f32x16 oA[2] = { Z16, Z16 }, oB[2] = { Z16, Z16 };
  float lA = 0.f, lB = 0.f;

  // prologue: stage tile 0 into buf 0
  #pragma unroll
  for (int j = 0; j < 4; ++j){
    gll16(ak0 + j * 1024,  &Ks[0][wave * 512] + j * 1024);
    gll16(av0 + j * 16384, &Vt[0][wave * 512] + j * 1024);
  }

  #pragma unroll 1
  for (int t = 0; t < 16; ++t){
    const int cur = t & 1, nxt = cur ^ 1;
    const u16* ksb = &Ks[cur][0];
    const u16* vsb = &Vt[cur][0];
    u16* kst = &Ks[nxt][wave * 512];
    u16* vst = &Vt[nxt][wave * 512];
    const u16* akg = ak0 + (size_t)(t + 1) * 4096;
    const u16* avg = av0 + (t + 1) * 64;

    // tile-start sync: my prefetch landed; both waves done reading the other buffer
    asm volatile("s_waitcnt vmcnt(0)" ::: "memory");
    __builtin_amdgcn_s_barrier();
    SB0();   // buf[cur] reads must not hoist above the barrier

    unsigned wA[8], wB[8];
    float psA = 0.f, psB = 0.f;

    // QK^T sub0 (kv 0..31): K-frag shared by both q-sets
    {
      f32x16 aA = Z16, aB = Z16;
      __builtin_amdgcn_s_setprio(1);
      #pragma unroll
      for (int ks = 0; ks < 4; ++ks){
        short8 kf = *(const short8*)(ksb + l31 * 64 + (((ks * 2 + hi) ^ x7) << 3));
        aA = MFMA32(kf, qfA[ks], aA);
        aB = MFMA32(kf, qfB[ks], aB);
      }
      __builtin_amdgcn_s_setprio(0);

      // stage next tile (t=15 stages harmless garbage; never consumed)
      #pragma unroll
      for (int j = 0; j < 4; ++j){
        gll16(akg + j * 1024,  kst + j * 1024);
        gll16(avg + j * 16384, vst + j * 1024);
      }

      #pragma unroll
      for (int tt2 = 0; tt2 < 8; ++tt2){
        float a0 = fexp2(aA[2 * tt2]), a1 = fexp2(aA[2 * tt2 + 1]);
        psA += a0 + a1; wA[tt2] = cvtpk(a0, a1);
        float b0 = fexp2(aB[2 * tt2]), b1 = fexp2(aB[2 * tt2 + 1]);
        psB += b0 + b1; wB[tt2] = cvtpk(b0, b1);
      }
    }
    // PV for kv 0..31 (sl 0,1): V-frag shared by both q-sets
    __builtin_amdgcn_s_setprio(1);
    #pragma unroll
    for (int sl = 0; sl < 2; ++sl){
      union { unsigned u[4]; short8 s; } bA, bB;
      bA.u[0] = wA[sl * 4 + 0]; bA.u[1] = wA[sl * 4 + 1];
      bA.u[2] = wA[sl * 4 + 2]; bA.u[3] = wA[sl * 4 + 3];
      bB.u[0] = wB[sl * 4 + 0]; bB.u[1] = wB[sl * 4 + 1];
      bB.u[2] = wB[sl * 4 + 2]; bB.u[3] = wB[sl * 4 + 3];
      #pragma unroll
      for (int dt = 0; dt < 2; ++dt){
        short8 vf = *(const short8*)(vsb + (dt * 32 + l31) * 64 + (((sl * 2 + hi) ^ x7) << 3));
        oA[dt] = MFMA32(vf, bA.s, oA[dt]);
        oB[dt] = MFMA32(vf, bB.s, oB[dt]);
      }
    }
    __builtin_amdgcn_s_setprio(0);

    // QK^T sub1 (kv 32..63) + exp/pack
    {
      f32x16 aA = Z16, aB = Z16;
      __builtin_amdgcn_s_setprio(1);
      #pragma unroll
      for (int ks = 0; ks < 4; ++ks){
        short8 kf = *(const short8*)(ksb + (32 + l31) * 64 + (((ks * 2 + hi) ^ x7) << 3));
        aA = MFMA32(kf, qfA[ks], aA);
        aB = MFMA32(kf, qfB[ks], aB);
      }
      __builtin_amdgcn_s_setprio(0);
      #pragma unroll
      for (int tt2 = 0; tt2 < 8; ++tt2){
        float a0 = fexp2(aA[2 * tt2]), a1 = fexp2(aA[2 * tt2 + 1]);
        psA += a0 + a1; wA[tt2] = cvtpk(a0, a1);
        float b0 = fexp2(aB[2 * tt2]), b1 = fexp2(aB[2 * tt2 + 1]);
        psB += b0 + b1; wB[tt2] = cvtpk(b0, b1);
      }
    }
    lA += psA; lB += psB;
    // PV for kv 32..63 (sl 2,3)
    __builtin_amdgcn_s_setprio(1);
    #pragma unroll
    for (int sl = 2; sl < 4; ++sl){
      union { unsigned u[4]; short8 s; } bA, bB;
      bA.u[0] = wA[(sl - 2) * 4 + 0]; bA.u[1] = wA[(sl - 2) * 4 + 1];
      bA.u[2] = wA[(sl - 2) * 4 + 2]; bA.u[3] = wA[(sl - 2) * 4 + 3];
      bB.u[0] = wB[(sl - 2) * 4 + 0]; bB.u[1] = wB[(sl - 2) * 4 + 1];
      bB.u[2] = wB[(sl - 2) * 4 + 2]; bB.u[3] = wB[(sl - 2) * 4 + 3];
      #pragma unroll
      for (int dt = 0; dt < 2; ++dt){
        short8 vf = *(const short8*)(vsb + (dt * 32 + l31) * 64 + (((sl * 2 + hi) ^ x7) << 3));
        oA[dt] = MFMA32(vf, bA.s, oA[dt]);
        oB[dt] = MFMA32(vf, bB.s, oB[dt]);
      }
    }
    __builtin_amdgcn_s_setprio(0);
  }

  float ltA = lA + __shfl_xor(lA, 32);
  float ltB = lB + __shfl_xor(lB, 32);
  float invA = 1.f / ltA, invB = 1.f / ltB;
  int b = bh >> 3, h = bh & 7;
  size_t obaseA = ((size_t)b * NQ + q0 + l31) * 512 + h * 64;
  size_t obaseB = obaseA + (size_t)32 * 512;
  #pragma unroll
  for (int dt = 0; dt < 2; ++dt)
    #pragma unroll
    for (int t = 0; t < 8; ++t){
      int j = 2 * t;
      int d = dt * 32 + (j & 3) + 8 * (j >> 2) + 4 * hi;
      *(unsigned*)(net + obaseA + d) = cvtpk(oA[dt][j] * invA, oA[dt][j + 1] * invA);
      *(unsigned*)(net + obaseB + d) = cvtpk(oB[dt][j] * invB, oB[dt][j + 1] * invB);
    }
}

extern "C" void kernel_launch(void* const* d_in, const int* in_sizes, int n_in,
                              void* d_out, int out_size, void* d_ws, size_t ws_size,
                              hipStream_t stream){
  const float* x      = (const float*)d_in[0];
  const float* q_w    = (const float*)d_in[1];
  const float* kv_w   = (const float*)d_in[2];
  const float* proj_w = (const float*)d_in[3];
  const float* proj_b = (const float*)d_in[4];
  const float* sr_w   = (const float*)d_in[5];
  const float* sr_b   = (const float*)d_in[6];
  const float* ln_w   = (const float*)d_in[7];
  const float* ln_b   = (const float*)d_in[8];
  (void)in_sizes; (void)n_in; (void)out_size; (void)ws_size;

  char* ws = (char*)d_ws;
  // Timeline-packed layout (68.5 MB total):
  // [0-16)  x_bf (prep->qconv)   -> after qconv: xr [0-4) (ln->kv), k_sb [4-8), vt_sb [8-12)
  // [16-48) conv partials z0..z3 (qconv->ln) -> after ln: net [16-32) (attn->proj)
  // [48-64) q_sb (qconv->attn)
  // [64-68.5) weights
  u16*   x_bf    = (u16*)(ws);
  u16*   xr      = (u16*)(ws);
  u16*   k_sb    = (u16*)(ws + ((size_t)4  << 20));
  u16*   vt_sb   = (u16*)(ws + ((size_t)8  << 20));
  float* parts   = (float*)(ws + ((size_t)16 << 20));
  u16*   net     = (u16*)(ws + ((size_t)16 << 20));
  u16*   q_sb    = (u16*)(ws + ((size_t)48 << 20));
  u16*   q_wT    = (u16*)(ws + ((size_t)64 << 20));
  u16*   kv_wT   = (u16*)(ws + ((size_t)64 << 20) + 524288);
  u16*   proj_wT = (u16*)(ws + ((size_t)64 << 20) + 524288 + 1048576);
  u16*   conv_BT = (u16*)(ws + ((size_t)64 << 20) + 524288 + 1048576 + 524288);
  float* out = (float*)d_out;

  prep_all<<<12288, 256, 0, stream>>>(x, q_w, kv_w, proj_w, sr_w,
                                      x_bf, q_wT, kv_wT, proj_wT, conv_BT);
  gemm_qconv<<<dim3(4, 256), 256, 0, stream>>>(x_bf, q_wT, conv_BT, q_sb, parts, sr_b);
  ln_k<<<1024, 256, 0, stream>>>(parts, ln_w, ln_b, xr);
  gemm_kv<<<dim3(8, 64), 256, 0, stream>>>(xr, kv_wT, k_sb, vt_sb);
  attn_k<<<1024, 128, 0, stream>>>(q_sb, k_sb, vt_sb, net);
  gemm_proj<<<dim3(4, 128), 256, 0, stream>>>(net, proj_wT, out, proj_b, 16384, 512, 512);
}

// Round 16
// 138.156 us; speedup vs baseline: 1.0125x; 1.0125x over previous
//
#include <hip/hip_runtime.h>
#include <cstdint>

#define HEADS 8
#define HD 64
#define NQ 4096
#define NKV 1024

typedef unsigned short u16;
typedef __attribute__((ext_vector_type(8))) short short8;
typedef __attribute__((ext_vector_type(4))) float f32x4;
typedef __attribute__((ext_vector_type(16))) float f32x16;

__device__ __forceinline__ u16 f2bf(float f){
  union { float f; unsigned u; } c; c.f = f;
  unsigned r = c.u + 0x7fffu + ((c.u >> 16) & 1u);
  return (u16)(r >> 16);
}
__device__ __forceinline__ unsigned pack2(float a, float b){
  return (unsigned)f2bf(a) | ((unsigned)f2bf(b) << 16);
}
__device__ __forceinline__ float fexp2(float x){
  float r;
  asm("v_exp_f32 %0, %1" : "=v"(r) : "v"(x));
  return r;
}
__device__ __forceinline__ unsigned cvtpk(float a, float b){
  unsigned r;
  asm("v_cvt_pk_bf16_f32 %0, %1, %2" : "=v"(r) : "v"(a), "v"(b));
  return r;
}
__device__ __forceinline__ void gll16(const void* g, void* l){
  __builtin_amdgcn_global_load_lds((const __attribute__((address_space(1))) unsigned*)g,
                                   (__attribute__((address_space(3))) unsigned*)l, 16, 0, 0);
}
#define SB0() __builtin_amdgcn_sched_barrier(0)
#define MFMA16(a, b, c) __builtin_amdgcn_mfma_f32_16x16x32_bf16(a, b, c, 0, 0, 0)
#define MFMA32(a, b, c) __builtin_amdgcn_mfma_f32_32x32x16_bf16(a, b, c, 0, 0, 0)
#define Z16 {0.f,0.f,0.f,0.f,0.f,0.f,0.f,0.f,0.f,0.f,0.f,0.f,0.f,0.f,0.f,0.f}

// ---- merged prep: x -> bf16 token layout; weights -> bf16 [N][K] ----
__global__ __launch_bounds__(256) void prep_all(const float* __restrict__ x,
                                                const float* __restrict__ q_w,
                                                const float* __restrict__ kv_w,
                                                const float* __restrict__ proj_w,
                                                const float* __restrict__ sr_w,
                                                u16* __restrict__ x_bf,
                                                u16* __restrict__ q_wT, u16* __restrict__ kv_wT,
                                                u16* __restrict__ proj_wT, u16* __restrict__ conv_BT){
  int bid = blockIdx.x;
  if (bid < 4096){
    int tid = bid * 256 + threadIdx.x;
    size_t src = (size_t)tid * 8;
    const float4* s4 = (const float4*)(x + src);
    float4 v0 = s4[0], v1 = s4[1];
    uint4 p;
    p.x = pack2(v0.x, v0.y); p.y = pack2(v0.z, v0.w);
    p.z = pack2(v1.x, v1.y); p.w = pack2(v1.z, v1.w);
    *(uint4*)(x_bf + src) = p;
    return;
  }
  int e = (bid - 4096) * 256 + threadIdx.x;
  if (e < 262144){ int n = e >> 9, k = e & 511; q_wT[e] = f2bf(q_w[k * 512 + n]); return; }
  e -= 262144;
  if (e < 524288){ int n = e >> 9, k = e & 511; kv_wT[e] = f2bf(kv_w[k * 1024 + n]); return; }
  e -= 524288;
  if (e < 262144){ int n = e >> 9, k = e & 511; proj_wT[e] = f2bf(proj_w[k * 512 + n]); return; }
  e -= 262144;
  { int co = e >> 11, r = e & 2047, t = r >> 9, ci = r & 511;
    conv_BT[e] = f2bf(sr_w[co * 2048 + ci * 4 + t]); }
}

// ---- fused conv-GEMM + q-GEMM. grid (4, 192): y<64 -> conv split-K2 (long first);
// y>=64 -> q. A read from x_bf (conv via patch remap). 128x128 tile, BK=64.
__global__ __launch_bounds__(256) void gemm_qconv(const u16* __restrict__ x_bf, const u16* __restrict__ q_wT,
                                                  const u16* __restrict__ conv_BT,
                                                  u16* __restrict__ q_sb, float* __restrict__ xr_pre,
                                                  const float* __restrict__ sr_b){
  __shared__ __align__(16) u16 As[128 * 64];
  __shared__ __align__(16) u16 Bs[128 * 64];
  const int tid = threadIdx.x, lane = tid & 63, wave = tid >> 6;
  const int l15 = lane & 15, g = lane >> 4, r7 = l15 & 7;
  const int wr = wave >> 1, wc = wave & 1;
  int y = blockIdx.y;
  const bool isQ = (y >= 64);
  int kz = 0, m0, kb = 0, iters, KB;
  const u16* BT;
  if (isQ){ m0 = (y - 64) * 128; iters = 8;  KB = 512;  BT = q_wT; }
  else { kz = y >> 5; m0 = (y & 31) * 128; kb = kz << 10; iters = 16; KB = 2048; BT = conv_BT; }
  const int n0 = blockIdx.x * 128;

  unsigned aBase[4], bBase[4];
  #pragma unroll
  for (int ii = 0; ii < 4; ++ii){
    int c = ii * 256 + tid;
    int row = c >> 3, sc = (c & 7) ^ (row & 7);
    if (isQ) aBase[ii] = (unsigned)(m0 + row) * 512 + sc * 8;
    else { int grow = m0 + row, b = grow >> 10, pr = grow & 1023;
           aBase[ii] = ((unsigned)(b * 4096) + (pr >> 5) * 128 + (pr & 31) * 2) * 512 + sc * 8; }
    bBase[ii] = (unsigned)(n0 + row) * KB + sc * 8;
  }

  f32x4 acc[4][4] = {};
  for (int i = 0; i < iters; ++i){
    int kt = kb + i * 64;
    unsigned aOff;
    if (isQ) aOff = kt;
    else { int t = kt >> 9; aOff = (unsigned)((t >> 1) * 64 + (t & 1)) * 512 + (kt & 511); }
    #pragma unroll
    for (int ii = 0; ii < 4; ++ii){
      gll16(x_bf + aBase[ii] + aOff, As + (size_t)(ii * 256 + wave * 64) * 8);
      gll16(BT + bBase[ii] + kt,     Bs + (size_t)(ii * 256 + wave * 64) * 8);
    }
    __syncthreads();
    #pragma unroll
    for (int kk = 0; kk < 2; ++kk){
      short8 af[4];
      #pragma unroll
      for (int mi = 0; mi < 4; ++mi)
        af[mi] = *(const short8*)(As + (wr * 64 + mi * 16 + l15) * 64 + (((kk * 4 + g) ^ r7) << 3));
      #pragma unroll
      for (int ni = 0; ni < 4; ++ni){
        short8 bf = *(const short8*)(Bs + (wc * 64 + ni * 16 + l15) * 64 + (((kk * 4 + g) ^ r7) << 3));
        #pragma unroll
        for (int mi = 0; mi < 4; ++mi)
          acc[mi][ni] = MFMA16(af[mi], bf, acc[mi][ni]);
      }
    }
    __syncthreads();
  }
  #pragma unroll
  for (int mi = 0; mi < 4; ++mi){
    int row = m0 + wr * 64 + mi * 16 + (lane >> 4) * 4;
    #pragma unroll
    for (int ni = 0; ni < 4; ++ni){
      int col = n0 + wc * 64 + ni * 16 + l15;
      f32x4 v = acc[mi][ni];
      if (isQ){
        int h = col >> 6, d = col & 63;
        #pragma unroll
        for (int j = 0; j < 4; ++j){
          int r = row + j, b = r >> 12, nq = r & 4095;
          q_sb[(((size_t)(b * HEADS + h)) * NQ + nq) * HD + d] = f2bf(v[j] * 0.18033688f);
        }
      } else {
        float* Co = xr_pre + (size_t)kz * 4096 * 512;
        float bb = (kz == 0) ? sr_b[col] : 0.f;
        #pragma unroll
        for (int j = 0; j < 4; ++j) Co[(size_t)(row + j) * 512 + col] = v[j] + bb;
      }
    }
  }
}

// ---- kv-GEMM: 64x128 tile, BK=64, 4 waves (2x2), grid (8,64) = 2/CU ----
__global__ __launch_bounds__(256) void gemm_kv(const u16* __restrict__ A, const u16* __restrict__ BT,
                                               u16* __restrict__ Cb0, u16* __restrict__ Cb1){
  __shared__ __align__(16) u16 As[64 * 64];
  __shared__ __align__(16) u16 Bs[128 * 64];
  const int tid = threadIdx.x, lane = tid & 63, wave = tid >> 6;
  const int l15 = lane & 15, g = lane >> 4, r7 = l15 & 7;
  const int m0 = blockIdx.y * 64, n0 = blockIdx.x * 128;
  const int wr = wave >> 1, wc = wave & 1;
  f32x4 acc[2][4] = {};
  for (int kt = 0; kt < 512; kt += 64){
    #pragma unroll
    for (int i = 0; i < 2; ++i){
      int c = i * 256 + tid;
      int row = c >> 3, sc = (c & 7) ^ (row & 7);
      gll16(A + (size_t)(m0 + row) * 512 + kt + sc * 8, As + (size_t)(i * 256 + wave * 64) * 8);
    }
    #pragma unroll
    for (int i = 0; i < 4; ++i){
      int c = i * 256 + tid;
      int row = c >> 3, sc = (c & 7) ^ (row & 7);
      gll16(BT + (size_t)(n0 + row) * 512 + kt + sc * 8, Bs + (size_t)(i * 256 + wave * 64) * 8);
    }
    __syncthreads();
    #pragma unroll
    for (int kk = 0; kk < 2; ++kk){
      short8 af[2];
      #pragma unroll
      for (int mi = 0; mi < 2; ++mi)
        af[mi] = *(const short8*)(As + (wr * 32 + mi * 16 + l15) * 64 + (((kk * 4 + g) ^ r7) << 3));
      #pragma unroll
      for (int ni = 0; ni < 4; ++ni){
        short8 bf = *(const short8*)(Bs + (wc * 64 + ni * 16 + l15) * 64 + (((kk * 4 + g) ^ r7) << 3));
        #pragma unroll
        for (int mi = 0; mi < 2; ++mi)
          acc[mi][ni] = MFMA16(af[mi], bf, acc[mi][ni]);
      }
    }
    __syncthreads();
  }
  #pragma unroll
  for (int mi = 0; mi < 2; ++mi){
    int row = m0 + wr * 32 + mi * 16 + (lane >> 4) * 4;
    #pragma unroll
    for (int ni = 0; ni < 4; ++ni){
      int col = n0 + wc * 64 + ni * 16 + l15;
      f32x4 v = acc[mi][ni];
      int s = col >> 9, h = (col >> 6) & 7, d = col & 63;
      if (s == 0){
        #pragma unroll
        for (int j = 0; j < 4; ++j){
          int r = row + j, b = r >> 10, p = r & 1023;
          Cb0[(((size_t)(b * HEADS + h)) * NKV + p) * HD + d] = f2bf(v[j]);
        }
      } else {                  // V^T: [bh][d][pi(p)], pi = swap quads 1<->2 per 16-block
        int b = row >> 10, p0 = row & 1023;
        int pp = (p0 & ~12) | (((p0 >> 2) & 1) << 3) | (((p0 >> 3) & 1) << 2);
        ushort4 pk;
        pk.x = f2bf(v[0]); pk.y = f2bf(v[1]); pk.z = f2bf(v[2]); pk.w = f2bf(v[3]);
        *(ushort4*)(Cb1 + (((size_t)(b * HEADS + h)) * HD + d) * NKV + pp) = pk;
      }
    }
  }
}

// ---- proj GEMM: 128x64 tile (4 blocks/CU), BK=64, fp32 out (+bias) ----
__global__ __launch_bounds__(256) void gemm_proj(const u16* __restrict__ A, const u16* __restrict__ BT,
                                                 float* __restrict__ Cf, const float* __restrict__ bias,
                                                 int M, int N, int K){
  __shared__ __align__(16) u16 As[128 * 64];
  __shared__ __align__(16) u16 Bs[64 * 64];
  const int tid = threadIdx.x, lane = tid & 63, wave = tid >> 6;
  const int l15 = lane & 15, g = lane >> 4, r7 = l15 & 7;
  const int m0 = blockIdx.y * 128, n0 = blockIdx.x * 64;
  const int wr = wave >> 1, wc = wave & 1;
  f32x4 acc[4][2] = {};
  for (int kt = 0; kt < K; kt += 64){
    #pragma unroll
    for (int i = 0; i < 4; ++i){
      int c = i * 256 + tid;
      int row = c >> 3, sc = (c & 7) ^ (row & 7);
      gll16(A + (size_t)(m0 + row) * K + kt + sc * 8, As + (size_t)(i * 256 + wave * 64) * 8);
    }
    #pragma unroll
    for (int i = 0; i < 2; ++i){
      int c = i * 256 + tid;
      int row = c >> 3, sc = (c & 7) ^ (row & 7);
      gll16(BT + (size_t)(n0 + row) * K + kt + sc * 8, Bs + (size_t)(i * 256 + wave * 64) * 8);
    }
    __syncthreads();
    #pragma unroll
    for (int kk = 0; kk < 2; ++kk){
      short8 af[4];
      #pragma unroll
      for (int mi = 0; mi < 4; ++mi)
        af[mi] = *(const short8*)(As + (wr * 64 + mi * 16 + l15) * 64 + (((kk * 4 + g) ^ r7) << 3));
      #pragma unroll
      for (int ni = 0; ni < 2; ++ni){
        short8 bf = *(const short8*)(Bs + (wc * 32 + ni * 16 + l15) * 64 + (((kk * 4 + g) ^ r7) << 3));
        #pragma unroll
        for (int mi = 0; mi < 4; ++mi)
          acc[mi][ni] = MFMA16(af[mi], bf, acc[mi][ni]);
      }
    }
    __syncthreads();
  }
  #pragma unroll
  for (int mi = 0; mi < 4; ++mi){
    int row = m0 + wr * 64 + mi * 16 + (lane >> 4) * 4;
    #pragma unroll
    for (int ni = 0; ni < 2; ++ni){
      int col = n0 + wc * 32 + ni * 16 + l15;
      f32x4 v = acc[mi][ni];
      float bb = bias[col];
      #pragma unroll
      for (int j = 0; j < 4; ++j) Cf[(size_t)(row + j) * N + col] = v[j] + bb;
    }
  }
}

// ---- LayerNorm over 512 cols; sums two split-K partials; fp32 in, bf16 out ----
__global__ __launch_bounds__(256) void ln_k(const float* __restrict__ xp,
                                            const float* __restrict__ w,
                                            const float* __restrict__ bias, u16* __restrict__ xr){
  int row = blockIdx.x * 4 + (threadIdx.x >> 6);
  int lane = threadIdx.x & 63;
  const float* s1 = xp + (size_t)row * 512;
  const float* s2 = s1 + (size_t)4096 * 512;
  float vals[8]; float s = 0.f, ss = 0.f;
  #pragma unroll
  for (int j = 0; j < 8; ++j){
    int c = lane + j * 64;
    float v = s1[c] + s2[c];
    vals[j] = v; s += v; ss += v * v;
  }
  #pragma unroll
  for (int off = 32; off >= 1; off >>= 1){ s += __shfl_xor(s, off); ss += __shfl_xor(ss, off); }
  float mean = s * (1.f / 512.f);
  float var  = ss * (1.f / 512.f) - mean * mean;
  float rs = rsqrtf(var + 1e-5f);
  u16* dst = xr + (size_t)row * 512;
  #pragma unroll
  for (int j = 0; j < 8; ++j){
    int c = lane + j * 64;
    dst[c] = f2bf((vals[j] - mean) * rs * w[c] + bias[c]);
  }
}

// ---- flash attention v12: 2 waves x 64 q-rows (2 q-sets share every K/V frag) ----
// q pre-scaled by (1/8)*log2(e) so p = 2^s; no-max softmax; zero-shuffle PV (pi-V).
template<bool LAST>
__device__ __forceinline__ void attn_tile(const u16* ksb, const u16* vsb,
                                          u16* kstage, u16* vstage,
                                          const u16* akg, const u16* avg,
                                          const short8* qfA, const short8* qfB,
                                          int l31, int hi, int x7,
                                          f32x16* oA, f32x16* oB,
                                          float& lA, float& lB){
  // tile-start sync: my prefetch landed; both waves done reading the other buffer
  asm volatile("s_waitcnt vmcnt(0)" ::: "memory");
  __builtin_amdgcn_s_barrier();
  SB0();   // buf[cur] reads must not hoist above the barrier

  unsigned wA[8], wB[8];
  float psA = 0.f, psB = 0.f;

  // QK^T sub0 (kv 0..31): K-frag shared by both q-sets
  {
    f32x16 aA = Z16, aB = Z16;
    __builtin_amdgcn_s_setprio(1);
    #pragma unroll
    for (int ks = 0; ks < 4; ++ks){
      short8 kf = *(const short8*)(ksb + l31 * 64 + (((ks * 2 + hi) ^ x7) << 3));
      aA = MFMA32(kf, qfA[ks], aA);
      aB = MFMA32(kf, qfB[ks], aB);
    }
    __builtin_amdgcn_s_setprio(0);

    // stage next tile (4 K chunks + 4 V chunks); overlaps exp/PV below
    if (!LAST){
      #pragma unroll
      for (int j = 0; j < 4; ++j){
        gll16(akg + j * 1024,  kstage + j * 1024);
        gll16(avg + j * 16384, vstage + j * 1024);
      }
    }

    #pragma unroll
    for (int t = 0; t < 8; ++t){
      float a0 = fexp2(aA[2 * t]), a1 = fexp2(aA[2 * t + 1]);
      psA += a0 + a1; wA[t] = cvtpk(a0, a1);
      float b0 = fexp2(aB[2 * t]), b1 = fexp2(aB[2 * t + 1]);
      psB += b0 + b1; wB[t] = cvtpk(b0, b1);
    }
  }
  // PV for kv 0..31 (sl 0,1): V-frag shared by both q-sets
  __builtin_amdgcn_s_setprio(1);
  #pragma unroll
  for (int sl = 0; sl < 2; ++sl){
    union { unsigned u[4]; short8 s; } bA, bB;
    bA.u[0] = wA[sl * 4 + 0]; bA.u[1] = wA[sl * 4 + 1];
    bA.u[2] = wA[sl * 4 + 2]; bA.u[3] = wA[sl * 4 + 3];
    bB.u[0] = wB[sl * 4 + 0]; bB.u[1] = wB[sl * 4 + 1];
    bB.u[2] = wB[sl * 4 + 2]; bB.u[3] = wB[sl * 4 + 3];
    #pragma unroll
    for (int dt = 0; dt < 2; ++dt){
      short8 vf = *(const short8*)(vsb + (dt * 32 + l31) * 64 + (((sl * 2 + hi) ^ x7) << 3));
      oA[dt] = MFMA32(vf, bA.s, oA[dt]);
      oB[dt] = MFMA32(vf, bB.s, oB[dt]);
    }
  }
  __builtin_amdgcn_s_setprio(0);

  // QK^T sub1 (kv 32..63) + exp/pack
  {
    f32x16 aA = Z16, aB = Z16;
    __builtin_amdgcn_s_setprio(1);
    #pragma unroll
    for (int ks = 0; ks < 4; ++ks){
      short8 kf = *(const short8*)(ksb + (32 + l31) * 64 + (((ks * 2 + hi) ^ x7) << 3));
      aA = MFMA32(kf, qfA[ks], aA);
      aB = MFMA32(kf, qfB[ks], aB);
    }
    __builtin_amdgcn_s_setprio(0);
    #pragma unroll
    for (int t = 0; t < 8; ++t){
      float a0 = fexp2(aA[2 * t]), a1 = fexp2(aA[2 * t + 1]);
      psA += a0 + a1; wA[t] = cvtpk(a0, a1);
      float b0 = fexp2(aB[2 * t]), b1 = fexp2(aB[2 * t + 1]);
      psB += b0 + b1; wB[t] = cvtpk(b0, b1);
    }
  }
  lA += psA; lB += psB;
  // PV for kv 32..63 (sl 2,3)
  __builtin_amdgcn_s_setprio(1);
  #pragma unroll
  for (int sl = 2; sl < 4; ++sl){
    union { unsigned u[4]; short8 s; } bA, bB;
    bA.u[0] = wA[(sl - 2) * 4 + 0]; bA.u[1] = wA[(sl - 2) * 4 + 1];
    bA.u[2] = wA[(sl - 2) * 4 + 2]; bA.u[3] = wA[(sl - 2) * 4 + 3];
    bB.u[0] = wB[(sl - 2) * 4 + 0]; bB.u[1] = wB[(sl - 2) * 4 + 1];
    bB.u[2] = wB[(sl - 2) * 4 + 2]; bB.u[3] = wB[(sl - 2) * 4 + 3];
    #pragma unroll
    for (int dt = 0; dt < 2; ++dt){
      short8 vf = *(const short8*)(vsb + (dt * 32 + l31) * 64 + (((sl * 2 + hi) ^ x7) << 3));
      oA[dt] = MFMA32(vf, bA.s, oA[dt]);
      oB[dt] = MFMA32(vf, bB.s, oB[dt]);
    }
  }
  __builtin_amdgcn_s_setprio(0);
}

// grid 1024 x 128 threads (2 waves): xcd=id&7 owns 4 bh; slot>>5 = bh-in-xcd,
// slot&31 = qblk; wave covers 64 q-rows (2 q-sets of 32).
__global__ __launch_bounds__(128) void attn_k(const u16* __restrict__ q_s, const u16* __restrict__ k_s,
                                              const u16* __restrict__ vt_s, u16* __restrict__ net){
  __shared__ __align__(16) u16 Ks[2][64 * 64];
  __shared__ __align__(16) u16 Vt[2][64 * 64];
  const int tid = threadIdx.x, lane = tid & 63, wave = tid >> 6;
  const int l31 = lane & 31, hi = lane >> 5, x7 = lane & 7;
  const int id = blockIdx.x;
  const int xcd = id & 7, slot = id >> 3;
  const int bh = 4 * xcd + (slot >> 5);
  const int qblk = slot & 31;
  const u16* kb  = k_s  + (size_t)bh * NKV * HD;
  const u16* vtb = vt_s + (size_t)bh * HD * NKV;
  const int q0 = qblk * 128 + wave * 64;
  const u16* qbase = q_s + ((size_t)bh * NQ + q0 + l31) * HD + hi * 8;
  short8 qfA[4], qfB[4];
  #pragma unroll
  for (int ks = 0; ks < 4; ++ks){
    qfA[ks] = *(const short8*)(qbase + ks * 16);
    qfB[ks] = *(const short8*)(qbase + 32 * HD + ks * 16);
  }

  // per-lane pre-swizzled global staging addresses (chunk ^= row&7; LDS stays linear)
  const int swz8 = (((tid & 7) ^ ((tid >> 3) & 7)) << 3);
  const u16* ak0 = kb  + (size_t)(tid >> 3) * 64   + swz8;
  const u16* av0 = vtb + (size_t)(tid >> 3) * 1024 + swz8;

  f32x16 oA[2] = { Z16, Z16 }, oB[2] = { Z16, Z16 };
  float lA = 0.f, lB = 0.f;

  u16* k0 = &Ks[0][wave * 512];
  u16* v0 = &Vt[0][wave * 512];
  u16* k1 = &Ks[1][wave * 512];
  u16* v1 = &Vt[1][wave * 512];

  // prologue: stage tile 0 into buf 0
  #pragma unroll
  for (int j = 0; j < 4; ++j){
    gll16(ak0 + j * 1024,  k0 + j * 1024);
    gll16(av0 + j * 16384, v0 + j * 1024);
  }

  for (int tt = 0; tt < 7; ++tt){
    attn_tile<false>(&Ks[0][0], &Vt[0][0], k1, v1,
                     ak0 + (size_t)(2 * tt + 1) * 4096, av0 + (2 * tt + 1) * 64,
                     qfA, qfB, l31, hi, x7, oA, oB, lA, lB);
    attn_tile<false>(&Ks[1][0], &Vt[1][0], k0, v0,
                     ak0 + (size_t)(2 * tt + 2) * 4096, av0 + (2 * tt + 2) * 64,
                     qfA, qfB, l31, hi, x7, oA, oB, lA, lB);
  }
  attn_tile<false>(&Ks[0][0], &Vt[0][0], k1, v1,
                   ak0 + (size_t)15 * 4096, av0 + 15 * 64,
                   qfA, qfB, l31, hi, x7, oA, oB, lA, lB);
  attn_tile<true>(&Ks[1][0], &Vt[1][0], nullptr, nullptr, nullptr, nullptr,
                  qfA, qfB, l31, hi, x7, oA, oB, lA, lB);

  float ltA = lA + __shfl_xor(lA, 32);
  float ltB = lB + __shfl_xor(lB, 32);
  float invA = 1.f / ltA, invB = 1.f / ltB;
  int b = bh >> 3, h = bh & 7;
  size_t obaseA = ((size_t)b * NQ + q0 + l31) * 512 + h * 64;
  size_t obaseB = obaseA + (size_t)32 * 512;
  #pragma unroll
  for (int dt = 0; dt < 2; ++dt)
    #pragma unroll
    for (int t = 0; t < 8; ++t){
      int j = 2 * t;
      int d = dt * 32 + (j & 3) + 8 * (j >> 2) + 4 * hi;
      *(unsigned*)(net + obaseA + d) = cvtpk(oA[dt][j] * invA, oA[dt][j + 1] * invA);
      *(unsigned*)(net + obaseB + d) = cvtpk(oB[dt][j] * invB, oB[dt][j + 1] * invB);
    }
}

extern "C" void kernel_launch(void* const* d_in, const int* in_sizes, int n_in,
                              void* d_out, int out_size, void* d_ws, size_t ws_size,
                              hipStream_t stream){
  const float* x      = (const float*)d_in[0];
  const float* q_w    = (const float*)d_in[1];
  const float* kv_w   = (const float*)d_in[2];
  const float* proj_w = (const float*)d_in[3];
  const float* proj_b = (const float*)d_in[4];
  const float* sr_w   = (const float*)d_in[5];
  const float* sr_b   = (const float*)d_in[6];
  const float* ln_w   = (const float*)d_in[7];
  const float* ln_b   = (const float*)d_in[8];
  (void)in_sizes; (void)n_in; (void)out_size; (void)ws_size;

  char* ws = (char*)d_ws;
  u16*   x_bf    = (u16*)(ws);                               // 0..16 MB (live through qconv)
  u16*   xr      = (u16*)(ws + ((size_t)16 << 20));          // 16..20 MB (dead after kv gemm)
  u16*   net     = (u16*)(ws + ((size_t)16 << 20));          // 16..32 MB (attn output)
  u16*   q_sb    = (u16*)(ws + ((size_t)32 << 20));          // 32..48 MB
  float* xr_pre  = (float*)(ws + ((size_t)48 << 20));        // conv partials z0,z1 (48..64 MB)
  u16*   k_sb    = (u16*)(ws + ((size_t)48 << 20));          // 48..52 MB (after ln)
  u16*   vt_sb   = (u16*)(ws + ((size_t)52 << 20));          // 52..56 MB (V^T [bh][d][pi(p)])
  u16*   q_wT    = (u16*)(ws + ((size_t)64 << 20));
  u16*   kv_wT   = (u16*)(ws + ((size_t)64 << 20) + 524288);
  u16*   proj_wT = (u16*)(ws + ((size_t)64 << 20) + 524288 + 1048576);
  u16*   conv_BT = (u16*)(ws + ((size_t)64 << 20) + 524288 + 1048576 + 524288);
  float* out = (float*)d_out;

  prep_all<<<12288, 256, 0, stream>>>(x, q_w, kv_w, proj_w, sr_w,
                                      x_bf, q_wT, kv_wT, proj_wT, conv_BT);
  gemm_qconv<<<dim3(4, 192), 256, 0, stream>>>(x_bf, q_wT, conv_BT, q_sb, xr_pre, sr_b);
  ln_k<<<1024, 256, 0, stream>>>(xr_pre, ln_w, ln_b, xr);
  gemm_kv<<<dim3(8, 64), 256, 0, stream>>>(xr, kv_wT, k_sb, vt_sb);
  attn_k<<<1024, 128, 0, stream>>>(q_sb, k_sb, vt_sb, net);
  gemm_proj<<<dim3(8, 128), 256, 0, stream>>>(net, proj_wT, out, proj_b, 16384, 512, 512);
}

// Round 17
// 131.155 us; speedup vs baseline: 1.0666x; 1.0534x over previous
//
#include <hip/hip_runtime.h>
#include <cstdint>

#define HEADS 8
#define HD 64
#define NQ 4096
#define NKV 1024

typedef unsigned short u16;
typedef __attribute__((ext_vector_type(8))) short short8;
typedef __attribute__((ext_vector_type(4))) float f32x4;
typedef __attribute__((ext_vector_type(16))) float f32x16;

__device__ __forceinline__ u16 f2bf(float f){
  union { float f; unsigned u; } c; c.f = f;
  unsigned r = c.u + 0x7fffu + ((c.u >> 16) & 1u);
  return (u16)(r >> 16);
}
__device__ __forceinline__ unsigned pack2(float a, float b){
  return (unsigned)f2bf(a) | ((unsigned)f2bf(b) << 16);
}
__device__ __forceinline__ float fexp2(float x){
  float r;
  asm("v_exp_f32 %0, %1" : "=v"(r) : "v"(x));
  return r;
}
__device__ __forceinline__ unsigned cvtpk(float a, float b){
  unsigned r;
  asm("v_cvt_pk_bf16_f32 %0, %1, %2" : "=v"(r) : "v"(a), "v"(b));
  return r;
}
__device__ __forceinline__ void gll16(const void* g, void* l){
  __builtin_amdgcn_global_load_lds((const __attribute__((address_space(1))) unsigned*)g,
                                   (__attribute__((address_space(3))) unsigned*)l, 16, 0, 0);
}
#define SB0() __builtin_amdgcn_sched_barrier(0)
#define MFMA16(a, b, c) __builtin_amdgcn_mfma_f32_16x16x32_bf16(a, b, c, 0, 0, 0)
#define MFMA32(a, b, c) __builtin_amdgcn_mfma_f32_32x32x16_bf16(a, b, c, 0, 0, 0)
#define Z16 {0.f,0.f,0.f,0.f,0.f,0.f,0.f,0.f,0.f,0.f,0.f,0.f,0.f,0.f,0.f,0.f}

// ---- merged prep: x -> bf16 token layout; weights -> bf16 [N][K] ----
__global__ __launch_bounds__(256) void prep_all(const float* __restrict__ x,
                                                const float* __restrict__ q_w,
                                                const float* __restrict__ kv_w,
                                                const float* __restrict__ proj_w,
                                                const float* __restrict__ sr_w,
                                                u16* __restrict__ x_bf,
                                                u16* __restrict__ q_wT, u16* __restrict__ kv_wT,
                                                u16* __restrict__ proj_wT, u16* __restrict__ conv_BT){
  int bid = blockIdx.x;
  if (bid < 4096){
    int tid = bid * 256 + threadIdx.x;
    size_t src = (size_t)tid * 8;
    const float4* s4 = (const float4*)(x + src);
    float4 v0 = s4[0], v1 = s4[1];
    uint4 p;
    p.x = pack2(v0.x, v0.y); p.y = pack2(v0.z, v0.w);
    p.z = pack2(v1.x, v1.y); p.w = pack2(v1.z, v1.w);
    *(uint4*)(x_bf + src) = p;
    return;
  }
  int e = (bid - 4096) * 256 + threadIdx.x;
  if (e < 262144){ int n = e >> 9, k = e & 511; q_wT[e] = f2bf(q_w[k * 512 + n]); return; }
  e -= 262144;
  if (e < 524288){ int n = e >> 9, k = e & 511; kv_wT[e] = f2bf(kv_w[k * 1024 + n]); return; }
  e -= 524288;
  if (e < 262144){ int n = e >> 9, k = e & 511; proj_wT[e] = f2bf(proj_w[k * 512 + n]); return; }
  e -= 262144;
  { int co = e >> 11, r = e & 2047, t = r >> 9, ci = r & 511;
    conv_BT[e] = f2bf(sr_w[co * 2048 + ci * 4 + t]); }
}

// ---- fused conv-GEMM + q-GEMM. grid (4, 192): y<64 -> conv split-K2 (long first);
// y>=64 -> q. A read from x_bf (conv via patch remap). 128x128 tile, BK=64.
__global__ __launch_bounds__(256) void gemm_qconv(const u16* __restrict__ x_bf, const u16* __restrict__ q_wT,
                                                  const u16* __restrict__ conv_BT,
                                                  u16* __restrict__ q_sb, float* __restrict__ xr_pre,
                                                  const float* __restrict__ sr_b){
  __shared__ __align__(16) u16 As[128 * 64];
  __shared__ __align__(16) u16 Bs[128 * 64];
  const int tid = threadIdx.x, lane = tid & 63, wave = tid >> 6;
  const int l15 = lane & 15, g = lane >> 4, r7 = l15 & 7;
  const int wr = wave >> 1, wc = wave & 1;
  int y = blockIdx.y;
  const bool isQ = (y >= 64);
  int kz = 0, m0, kb = 0, iters, KB;
  const u16* BT;
  if (isQ){ m0 = (y - 64) * 128; iters = 8;  KB = 512;  BT = q_wT; }
  else { kz = y >> 5; m0 = (y & 31) * 128; kb = kz << 10; iters = 16; KB = 2048; BT = conv_BT; }
  const int n0 = blockIdx.x * 128;

  unsigned aBase[4], bBase[4];
  #pragma unroll
  for (int ii = 0; ii < 4; ++ii){
    int c = ii * 256 + tid;
    int row = c >> 3, sc = (c & 7) ^ (row & 7);
    if (isQ) aBase[ii] = (unsigned)(m0 + row) * 512 + sc * 8;
    else { int grow = m0 + row, b = grow >> 10, pr = grow & 1023;
           aBase[ii] = ((unsigned)(b * 4096) + (pr >> 5) * 128 + (pr & 31) * 2) * 512 + sc * 8; }
    bBase[ii] = (unsigned)(n0 + row) * KB + sc * 8;
  }

  f32x4 acc[4][4] = {};
  for (int i = 0; i < iters; ++i){
    int kt = kb + i * 64;
    unsigned aOff;
    if (isQ) aOff = kt;
    else { int t = kt >> 9; aOff = (unsigned)((t >> 1) * 64 + (t & 1)) * 512 + (kt & 511); }
    #pragma unroll
    for (int ii = 0; ii < 4; ++ii){
      gll16(x_bf + aBase[ii] + aOff, As + (size_t)(ii * 256 + wave * 64) * 8);
      gll16(BT + bBase[ii] + kt,     Bs + (size_t)(ii * 256 + wave * 64) * 8);
    }
    __syncthreads();
    #pragma unroll
    for (int kk = 0; kk < 2; ++kk){
      short8 af[4];
      #pragma unroll
      for (int mi = 0; mi < 4; ++mi)
        af[mi] = *(const short8*)(As + (wr * 64 + mi * 16 + l15) * 64 + (((kk * 4 + g) ^ r7) << 3));
      #pragma unroll
      for (int ni = 0; ni < 4; ++ni){
        short8 bf = *(const short8*)(Bs + (wc * 64 + ni * 16 + l15) * 64 + (((kk * 4 + g) ^ r7) << 3));
        #pragma unroll
        for (int mi = 0; mi < 4; ++mi)
          acc[mi][ni] = MFMA16(af[mi], bf, acc[mi][ni]);
      }
    }
    __syncthreads();
  }
  #pragma unroll
  for (int mi = 0; mi < 4; ++mi){
    int row = m0 + wr * 64 + mi * 16 + (lane >> 4) * 4;
    #pragma unroll
    for (int ni = 0; ni < 4; ++ni){
      int col = n0 + wc * 64 + ni * 16 + l15;
      f32x4 v = acc[mi][ni];
      if (isQ){
        int h = col >> 6, d = col & 63;
        #pragma unroll
        for (int j = 0; j < 4; ++j){
          int r = row + j, b = r >> 12, nq = r & 4095;
          q_sb[(((size_t)(b * HEADS + h)) * NQ + nq) * HD + d] = f2bf(v[j] * 0.18033688f);
        }
      } else {
        float* Co = xr_pre + (size_t)kz * 4096 * 512;
        float bb = (kz == 0) ? sr_b[col] : 0.f;
        #pragma unroll
        for (int j = 0; j < 4; ++j) Co[(size_t)(row + j) * 512 + col] = v[j] + bb;
      }
    }
  }
}

// ---- kv-GEMM: 64x128 tile, BK=64, 4 waves (2x2), grid (8,64) = 2/CU ----
__global__ __launch_bounds__(256) void gemm_kv(const u16* __restrict__ A, const u16* __restrict__ BT,
                                               u16* __restrict__ Cb0, u16* __restrict__ Cb1){
  __shared__ __align__(16) u16 As[64 * 64];
  __shared__ __align__(16) u16 Bs[128 * 64];
  const int tid = threadIdx.x, lane = tid & 63, wave = tid >> 6;
  const int l15 = lane & 15, g = lane >> 4, r7 = l15 & 7;
  const int m0 = blockIdx.y * 64, n0 = blockIdx.x * 128;
  const int wr = wave >> 1, wc = wave & 1;
  f32x4 acc[2][4] = {};
  for (int kt = 0; kt < 512; kt += 64){
    #pragma unroll
    for (int i = 0; i < 2; ++i){
      int c = i * 256 + tid;
      int row = c >> 3, sc = (c & 7) ^ (row & 7);
      gll16(A + (size_t)(m0 + row) * 512 + kt + sc * 8, As + (size_t)(i * 256 + wave * 64) * 8);
    }
    #pragma unroll
    for (int i = 0; i < 4; ++i){
      int c = i * 256 + tid;
      int row = c >> 3, sc = (c & 7) ^ (row & 7);
      gll16(BT + (size_t)(n0 + row) * 512 + kt + sc * 8, Bs + (size_t)(i * 256 + wave * 64) * 8);
    }
    __syncthreads();
    #pragma unroll
    for (int kk = 0; kk < 2; ++kk){
      short8 af[2];
      #pragma unroll
      for (int mi = 0; mi < 2; ++mi)
        af[mi] = *(const short8*)(As + (wr * 32 + mi * 16 + l15) * 64 + (((kk * 4 + g) ^ r7) << 3));
      #pragma unroll
      for (int ni = 0; ni < 4; ++ni){
        short8 bf = *(const short8*)(Bs + (wc * 64 + ni * 16 + l15) * 64 + (((kk * 4 + g) ^ r7) << 3));
        #pragma unroll
        for (int mi = 0; mi < 2; ++mi)
          acc[mi][ni] = MFMA16(af[mi], bf, acc[mi][ni]);
      }
    }
    __syncthreads();
  }
  #pragma unroll
  for (int mi = 0; mi < 2; ++mi){
    int row = m0 + wr * 32 + mi * 16 + (lane >> 4) * 4;
    #pragma unroll
    for (int ni = 0; ni < 4; ++ni){
      int col = n0 + wc * 64 + ni * 16 + l15;
      f32x4 v = acc[mi][ni];
      int s = col >> 9, h = (col >> 6) & 7, d = col & 63;
      if (s == 0){
        #pragma unroll
        for (int j = 0; j < 4; ++j){
          int r = row + j, b = r >> 10, p = r & 1023;
          Cb0[(((size_t)(b * HEADS + h)) * NKV + p) * HD + d] = f2bf(v[j]);
        }
      } else {                  // V^T: [bh][d][pi(p)], pi = swap quads 1<->2 per 16-block
        int b = row >> 10, p0 = row & 1023;
        int pp = (p0 & ~12) | (((p0 >> 2) & 1) << 3) | (((p0 >> 3) & 1) << 2);
        ushort4 pk;
        pk.x = f2bf(v[0]); pk.y = f2bf(v[1]); pk.z = f2bf(v[2]); pk.w = f2bf(v[3]);
        *(ushort4*)(Cb1 + (((size_t)(b * HEADS + h)) * HD + d) * NKV + pp) = pk;
      }
    }
  }
}

// ---- proj GEMM: C[M,N] = A[M,K] @ BT[N,K]^T, 128x128, BK=64, fp32 out (+bias) ----
__global__ __launch_bounds__(256) void gemm_proj(const u16* __restrict__ A, const u16* __restrict__ BT,
                                                 float* __restrict__ Cf, const float* __restrict__ bias,
                                                 int M, int N, int K){
  __shared__ __align__(16) u16 As[128 * 64];
  __shared__ __align__(16) u16 Bs[128 * 64];
  const int tid = threadIdx.x, lane = tid & 63, wave = tid >> 6;
  const int l15 = lane & 15, g = lane >> 4, r7 = l15 & 7;
  const int m0 = blockIdx.y * 128, n0 = blockIdx.x * 128;
  const int wr = wave >> 1, wc = wave & 1;
  f32x4 acc[4][4] = {};
  for (int kt = 0; kt < K; kt += 64){
    #pragma unroll
    for (int i = 0; i < 4; ++i){
      int c = i * 256 + tid;
      int row = c >> 3, sc = (c & 7) ^ (row & 7);
      gll16(A  + (size_t)(m0 + row) * K + kt + sc * 8, As + (size_t)(i * 256 + wave * 64) * 8);
      gll16(BT + (size_t)(n0 + row) * K + kt + sc * 8, Bs + (size_t)(i * 256 + wave * 64) * 8);
    }
    __syncthreads();
    #pragma unroll
    for (int kk = 0; kk < 2; ++kk){
      short8 af[4];
      #pragma unroll
      for (int mi = 0; mi < 4; ++mi)
        af[mi] = *(const short8*)(As + (wr * 64 + mi * 16 + l15) * 64 + (((kk * 4 + g) ^ r7) << 3));
      #pragma unroll
      for (int ni = 0; ni < 4; ++ni){
        short8 bf = *(const short8*)(Bs + (wc * 64 + ni * 16 + l15) * 64 + (((kk * 4 + g) ^ r7) << 3));
        #pragma unroll
        for (int mi = 0; mi < 4; ++mi)
          acc[mi][ni] = MFMA16(af[mi], bf, acc[mi][ni]);
      }
    }
    __syncthreads();
  }
  #pragma unroll
  for (int mi = 0; mi < 4; ++mi){
    int row = m0 + wr * 64 + mi * 16 + (lane >> 4) * 4;
    #pragma unroll
    for (int ni = 0; ni < 4; ++ni){
      int col = n0 + wc * 64 + ni * 16 + l15;
      f32x4 v = acc[mi][ni];
      float bb = bias[col];
      #pragma unroll
      for (int j = 0; j < 4; ++j) Cf[(size_t)(row + j) * N + col] = v[j] + bb;
    }
  }
}

// ---- LayerNorm over 512 cols; sums two split-K partials; fp32 in, bf16 out ----
__global__ __launch_bounds__(256) void ln_k(const float* __restrict__ xp,
                                            const float* __restrict__ w,
                                            const float* __restrict__ bias, u16* __restrict__ xr){
  int row = blockIdx.x * 4 + (threadIdx.x >> 6);
  int lane = threadIdx.x & 63;
  const float* s1 = xp + (size_t)row * 512;
  const float* s2 = s1 + (size_t)4096 * 512;
  float vals[8]; float s = 0.f, ss = 0.f;
  #pragma unroll
  for (int j = 0; j < 8; ++j){
    int c = lane + j * 64;
    float v = s1[c] + s2[c];
    vals[j] = v; s += v; ss += v * v;
  }
  #pragma unroll
  for (int off = 32; off >= 1; off >>= 1){ s += __shfl_xor(s, off); ss += __shfl_xor(ss, off); }
  float mean = s * (1.f / 512.f);
  float var  = ss * (1.f / 512.f) - mean * mean;
  float rs = rsqrtf(var + 1e-5f);
  u16* dst = xr + (size_t)row * 512;
  #pragma unroll
  for (int j = 0; j < 8; ++j){
    int c = lane + j * 64;
    dst[c] = f2bf((vals[j] - mean) * rs * w[c] + bias[c]);
  }
}

// ---- flash attention v12: 2 waves x 64 q-rows (2 q-sets share every K/V frag) ----
// q pre-scaled by (1/8)*log2(e) so p = 2^s; no-max softmax; zero-shuffle PV (pi-V).
template<bool LAST>
__device__ __forceinline__ void attn_tile(const u16* ksb, const u16* vsb,
                                          u16* kstage, u16* vstage,
                                          const u16* akg, const u16* avg,
                                          const short8* qfA, const short8* qfB,
                                          int l31, int hi, int x7,
                                          f32x16* oA, f32x16* oB,
                                          float& lA, float& lB){
  // tile-start sync: my prefetch landed; both waves done reading the other buffer
  asm volatile("s_waitcnt vmcnt(0)" ::: "memory");
  __builtin_amdgcn_s_barrier();
  SB0();   // buf[cur] reads must not hoist above the barrier

  unsigned wA[8], wB[8];
  float psA = 0.f, psB = 0.f;

  // QK^T sub0 (kv 0..31): K-frag shared by both q-sets
  {
    f32x16 aA = Z16, aB = Z16;
    __builtin_amdgcn_s_setprio(1);
    #pragma unroll
    for (int ks = 0; ks < 4; ++ks){
      short8 kf = *(const short8*)(ksb + l31 * 64 + (((ks * 2 + hi) ^ x7) << 3));
      aA = MFMA32(kf, qfA[ks], aA);
      aB = MFMA32(kf, qfB[ks], aB);
    }
    __builtin_amdgcn_s_setprio(0);

    // stage next tile (4 K chunks + 4 V chunks); overlaps exp/PV below
    if (!LAST){
      #pragma unroll
      for (int j = 0; j < 4; ++j){
        gll16(akg + j * 1024,  kstage + j * 1024);
        gll16(avg + j * 16384, vstage + j * 1024);
      }
    }

    #pragma unroll
    for (int t = 0; t < 8; ++t){
      float a0 = fexp2(aA[2 * t]), a1 = fexp2(aA[2 * t + 1]);
      psA += a0 + a1; wA[t] = cvtpk(a0, a1);
      float b0 = fexp2(aB[2 * t]), b1 = fexp2(aB[2 * t + 1]);
      psB += b0 + b1; wB[t] = cvtpk(b0, b1);
    }
  }
  // PV for kv 0..31 (sl 0,1): V-frag shared by both q-sets
  __builtin_amdgcn_s_setprio(1);
  #pragma unroll
  for (int sl = 0; sl < 2; ++sl){
    union { unsigned u[4]; short8 s; } bA, bB;
    bA.u[0] = wA[sl * 4 + 0]; bA.u[1] = wA[sl * 4 + 1];
    bA.u[2] = wA[sl * 4 + 2]; bA.u[3] = wA[sl * 4 + 3];
    bB.u[0] = wB[sl * 4 + 0]; bB.u[1] = wB[sl * 4 + 1];
    bB.u[2] = wB[sl * 4 + 2]; bB.u[3] = wB[sl * 4 + 3];
    #pragma unroll
    for (int dt = 0; dt < 2; ++dt){
      short8 vf = *(const short8*)(vsb + (dt * 32 + l31) * 64 + (((sl * 2 + hi) ^ x7) << 3));
      oA[dt] = MFMA32(vf, bA.s, oA[dt]);
      oB[dt] = MFMA32(vf, bB.s, oB[dt]);
    }
  }
  __builtin_amdgcn_s_setprio(0);

  // QK^T sub1 (kv 32..63) + exp/pack
  {
    f32x16 aA = Z16, aB = Z16;
    __builtin_amdgcn_s_setprio(1);
    #pragma unroll
    for (int ks = 0; ks < 4; ++ks){
      short8 kf = *(const short8*)(ksb + (32 + l31) * 64 + (((ks * 2 + hi) ^ x7) << 3));
      aA = MFMA32(kf, qfA[ks], aA);
      aB = MFMA32(kf, qfB[ks], aB);
    }
    __builtin_amdgcn_s_setprio(0);
    #pragma unroll
    for (int t = 0; t < 8; ++t){
      float a0 = fexp2(aA[2 * t]), a1 = fexp2(aA[2 * t + 1]);
      psA += a0 + a1; wA[t] = cvtpk(a0, a1);
      float b0 = fexp2(aB[2 * t]), b1 = fexp2(aB[2 * t + 1]);
      psB += b0 + b1; wB[t] = cvtpk(b0, b1);
    }
  }
  lA += psA; lB += psB;
  // PV for kv 32..63 (sl 2,3)
  __builtin_amdgcn_s_setprio(1);
  #pragma unroll
  for (int sl = 2; sl < 4; ++sl){
    union { unsigned u[4]; short8 s; } bA, bB;
    bA.u[0] = wA[(sl - 2) * 4 + 0]; bA.u[1] = wA[(sl - 2) * 4 + 1];
    bA.u[2] = wA[(sl - 2) * 4 + 2]; bA.u[3] = wA[(sl - 2) * 4 + 3];
    bB.u[0] = wB[(sl - 2) * 4 + 0]; bB.u[1] = wB[(sl - 2) * 4 + 1];
    bB.u[2] = wB[(sl - 2) * 4 + 2]; bB.u[3] = wB[(sl - 2) * 4 + 3];
    #pragma unroll
    for (int dt = 0; dt < 2; ++dt){
      short8 vf = *(const short8*)(vsb + (dt * 32 + l31) * 64 + (((sl * 2 + hi) ^ x7) << 3));
      oA[dt] = MFMA32(vf, bA.s, oA[dt]);
      oB[dt] = MFMA32(vf, bB.s, oB[dt]);
    }
  }
  __builtin_amdgcn_s_setprio(0);
}

// grid 1024 x 128 threads (2 waves): xcd=id&7 owns 4 bh; slot>>5 = bh-in-xcd,
// slot&31 = qblk; wave covers 64 q-rows (2 q-sets of 32).
__global__ __launch_bounds__(128) void attn_k(const u16* __restrict__ q_s, const u16* __restrict__ k_s,
                                              const u16* __restrict__ vt_s, u16* __restrict__ net){
  __shared__ __align__(16) u16 Ks[2][64 * 64];
  __shared__ __align__(16) u16 Vt[2][64 * 64];
  const int tid = threadIdx.x, lane = tid & 63, wave = tid >> 6;
  const int l31 = lane & 31, hi = lane >> 5, x7 = lane & 7;
  const int id = blockIdx.x;
  const int xcd = id & 7, slot = id >> 3;
  const int bh = 4 * xcd + (slot >> 5);
  const int qblk = slot & 31;
  const u16* kb  = k_s  + (size_t)bh * NKV * HD;
  const u16* vtb = vt_s + (size_t)bh * HD * NKV;
  const int q0 = qblk * 128 + wave * 64;
  const u16* qbase = q_s + ((size_t)bh * NQ + q0 + l31) * HD + hi * 8;
  short8 qfA[4], qfB[4];
  #pragma unroll
  for (int ks = 0; ks < 4; ++ks){
    qfA[ks] = *(const short8*)(qbase + ks * 16);
    qfB[ks] = *(const short8*)(qbase + 32 * HD + ks * 16);
  }

  // per-lane pre-swizzled global staging addresses (chunk ^= row&7; LDS stays linear)
  const int swz8 = (((tid & 7) ^ ((tid >> 3) & 7)) << 3);
  const u16* ak0 = kb  + (size_t)(tid >> 3) * 64   + swz8;
  const u16* av0 = vtb + (size_t)(tid >> 3) * 1024 + swz8;

  f32x16 oA[2] = { Z16, Z16 }, oB[2] = { Z16, Z16 };
  float lA = 0.f, lB = 0.f;

  u16* k0 = &Ks[0][wave * 512];
  u16* v0 = &Vt[0][wave * 512];
  u16* k1 = &Ks[1][wave * 512];
  u16* v1 = &Vt[1][wave * 512];

  // prologue: stage tile 0 into buf 0
  #pragma unroll
  for (int j = 0; j < 4; ++j){
    gll16(ak0 + j * 1024,  k0 + j * 1024);
    gll16(av0 + j * 16384, v0 + j * 1024);
  }

  for (int tt = 0; tt < 7; ++tt){
    attn_tile<false>(&Ks[0][0], &Vt[0][0], k1, v1,
                     ak0 + (size_t)(2 * tt + 1) * 4096, av0 + (2 * tt + 1) * 64,
                     qfA, qfB, l31, hi, x7, oA, oB, lA, lB);
    attn_tile<false>(&Ks[1][0], &Vt[1][0], k0, v0,
                     ak0 + (size_t)(2 * tt + 2) * 4096, av0 + (2 * tt + 2) * 64,
                     qfA, qfB, l31, hi, x7, oA, oB, lA, lB);
  }
  attn_tile<false>(&Ks[0][0], &Vt[0][0], k1, v1,
                   ak0 + (size_t)15 * 4096, av0 + 15 * 64,
                   qfA, qfB, l31, hi, x7, oA, oB, lA, lB);
  attn_tile<true>(&Ks[1][0], &Vt[1][0], nullptr, nullptr, nullptr, nullptr,
                  qfA, qfB, l31, hi, x7, oA, oB, lA, lB);

  float ltA = lA + __shfl_xor(lA, 32);
  float ltB = lB + __shfl_xor(lB, 32);
  float invA = 1.f / ltA, invB = 1.f / ltB;
  int b = bh >> 3, h = bh & 7;
  size_t obaseA = ((size_t)b * NQ + q0 + l31) * 512 + h * 64;
  size_t obaseB = obaseA + (size_t)32 * 512;
  #pragma unroll
  for (int dt = 0; dt < 2; ++dt)
    #pragma unroll
    for (int t = 0; t < 8; ++t){
      int j = 2 * t;
      int d = dt * 32 + (j & 3) + 8 * (j >> 2) + 4 * hi;
      *(unsigned*)(net + obaseA + d) = cvtpk(oA[dt][j] * invA, oA[dt][j + 1] * invA);
      *(unsigned*)(net + obaseB + d) = cvtpk(oB[dt][j] * invB, oB[dt][j + 1] * invB);
    }
}

extern "C" void kernel_launch(void* const* d_in, const int* in_sizes, int n_in,
                              void* d_out, int out_size, void* d_ws, size_t ws_size,
                              hipStream_t stream){
  const float* x      = (const float*)d_in[0];
  const float* q_w    = (const float*)d_in[1];
  const float* kv_w   = (const float*)d_in[2];
  const float* proj_w = (const float*)d_in[3];
  const float* proj_b = (const float*)d_in[4];
  const float* sr_w   = (const float*)d_in[5];
  const float* sr_b   = (const float*)d_in[6];
  const float* ln_w   = (const float*)d_in[7];
  const float* ln_b   = (const float*)d_in[8];
  (void)in_sizes; (void)n_in; (void)out_size; (void)ws_size;

  char* ws = (char*)d_ws;
  u16*   x_bf    = (u16*)(ws);                               // 0..16 MB (live through qconv)
  u16*   xr      = (u16*)(ws + ((size_t)16 << 20));          // 16..20 MB (dead after kv gemm)
  u16*   net     = (u16*)(ws + ((size_t)16 << 20));          // 16..32 MB (attn output)
  u16*   q_sb    = (u16*)(ws + ((size_t)32 << 20));          // 32..48 MB
  float* xr_pre  = (float*)(ws + ((size_t)48 << 20));        // conv partials z0,z1 (48..64 MB)
  u16*   k_sb    = (u16*)(ws + ((size_t)48 << 20));          // 48..52 MB (after ln)
  u16*   vt_sb   = (u16*)(ws + ((size_t)52 << 20));          // 52..56 MB (V^T [bh][d][pi(p)])
  u16*   q_wT    = (u16*)(ws + ((size_t)64 << 20));
  u16*   kv_wT   = (u16*)(ws + ((size_t)64 << 20) + 524288);
  u16*   proj_wT = (u16*)(ws + ((size_t)64 << 20) + 524288 + 1048576);
  u16*   conv_BT = (u16*)(ws + ((size_t)64 << 20) + 524288 + 1048576 + 524288);
  float* out = (float*)d_out;

  prep_all<<<12288, 256, 0, stream>>>(x, q_w, kv_w, proj_w, sr_w,
                                      x_bf, q_wT, kv_wT, proj_wT, conv_BT);
  gemm_qconv<<<dim3(4, 192), 256, 0, stream>>>(x_bf, q_wT, conv_BT, q_sb, xr_pre, sr_b);
  ln_k<<<1024, 256, 0, stream>>>(xr_pre, ln_w, ln_b, xr);
  gemm_kv<<<dim3(8, 64), 256, 0, stream>>>(xr, kv_wT, k_sb, vt_sb);
  attn_k<<<1024, 128, 0, stream>>>(q_sb, k_sb, vt_sb, net);
  gemm_proj<<<dim3(4, 128), 256, 0, stream>>>(net, proj_wT, out, proj_b, 16384, 512, 512);
}